// Round 1
// baseline (30.275 us; speedup 1.0000x reference)
//
#include <hip/hip_runtime.h>
#include <math.h>

// 4-qubit VQC forward: RX(x) product state -> 2 layers of [all-pairs CNOT + RY(weights)]
// -> <Z_w> per wire. One thread per sample; 16 complex amps live in registers.

__global__ void weights_trig_kernel(const float* __restrict__ w,
                                    float* __restrict__ ws) {
    int i = threadIdx.x;
    if (i < 8) {
        float a = w[i] * 0.5f;
        ws[2 * i]     = cosf(a);
        ws[2 * i + 1] = sinf(a);
    }
}

__global__ __launch_bounds__(256) void qsim_kernel(const float* __restrict__ x,
                                                   const float* __restrict__ wt,
                                                   float* __restrict__ out,
                                                   int B) {
    int i = blockIdx.x * blockDim.x + threadIdx.x;
    if (i >= B) return;

    // ---- load x (coalesced float4) and build RX product state ----
    float4 xv = reinterpret_cast<const float4*>(x)[i];
    float c[4], s[4];
    {
        float th;
        th = 0.5f * xv.x; c[0] = __cosf(th); s[0] = __sinf(th);
        th = 0.5f * xv.y; c[1] = __cosf(th); s[1] = __sinf(th);
        th = 0.5f * xv.z; c[2] = __cosf(th); s[2] = __sinf(th);
        th = 0.5f * xv.w; c[3] = __cosf(th); s[3] = __sinf(th);
    }

    // wire w -> bit (3-w) of flat index. amp[idx] = (-i)^k * p, k = popcount(idx)
    float re[16], im[16];
#pragma unroll
    for (int idx = 0; idx < 16; ++idx) {
        float p = ((idx & 8) ? s[0] : c[0]) * ((idx & 4) ? s[1] : c[1]) *
                  ((idx & 2) ? s[2] : c[2]) * ((idx & 1) ? s[3] : c[3]);
        int k = ((idx & 1) + ((idx >> 1) & 1) + ((idx >> 2) & 1) + ((idx >> 3) & 1)) & 3;
        re[idx] = (k == 0) ? p : ((k == 2) ? -p : 0.0f);
        im[idx] = (k == 1) ? -p : ((k == 3) ? p : 0.0f);
    }

    // ---- 2 layers: 6 CNOTs then RY on each wire ----
#pragma unroll
    for (int l = 0; l < 2; ++l) {
        // CNOT pairs (c,t): (0,1),(0,2),(0,3),(1,2),(1,3),(2,3)
#pragma unroll
        for (int q = 0; q < 6; ++q) {
            const int cw[6] = {0, 0, 0, 1, 1, 2};
            const int tw[6] = {1, 2, 3, 2, 3, 3};
            int mc = 8 >> cw[q];
            int mt = 8 >> tw[q];
#pragma unroll
            for (int idx = 0; idx < 16; ++idx) {
                if ((idx & mc) && !(idx & mt)) {
                    int j = idx | mt;
                    float tr = re[idx], ti = im[idx];
                    re[idx] = re[j]; im[idx] = im[j];
                    re[j] = tr;      im[j] = ti;
                }
            }
        }
        // RY(weights[l][w]) on each wire
#pragma unroll
        for (int w = 0; w < 4; ++w) {
            float ca = wt[2 * (l * 4 + w)];
            float sa = wt[2 * (l * 4 + w) + 1];
            int m = 8 >> w;
#pragma unroll
            for (int idx = 0; idx < 16; ++idx) {
                if (!(idx & m)) {
                    int j = idx | m;
                    float r0 = re[idx], i0 = im[idx];
                    float r1 = re[j],   i1 = im[j];
                    re[idx] = ca * r0 - sa * r1;
                    im[idx] = ca * i0 - sa * i1;
                    re[j]   = sa * r0 + ca * r1;
                    im[j]   = sa * i0 + ca * i1;
                }
            }
        }
    }

    // ---- <Z_w> = sum_{bit_w=0} |amp|^2 - sum_{bit_w=1} |amp|^2 ----
    float o0 = 0.f, o1 = 0.f, o2 = 0.f, o3 = 0.f;
#pragma unroll
    for (int idx = 0; idx < 16; ++idx) {
        float p = re[idx] * re[idx] + im[idx] * im[idx];
        o0 += (idx & 8) ? -p : p;
        o1 += (idx & 4) ? -p : p;
        o2 += (idx & 2) ? -p : p;
        o3 += (idx & 1) ? -p : p;
    }
    float4 ov = {o0, o1, o2, o3};
    reinterpret_cast<float4*>(out)[i] = ov;
}

extern "C" void kernel_launch(void* const* d_in, const int* in_sizes, int n_in,
                              void* d_out, int out_size, void* d_ws, size_t ws_size,
                              hipStream_t stream) {
    const float* x = (const float*)d_in[0];       // [B,4]
    const float* w = (const float*)d_in[1];       // [2,4]
    float* out = (float*)d_out;                   // [B,4]
    float* ws  = (float*)d_ws;                    // 16 floats: (cos,sin) per weight

    int B = in_sizes[0] / 4;

    weights_trig_kernel<<<1, 64, 0, stream>>>(w, ws);
    qsim_kernel<<<(B + 255) / 256, 256, 0, stream>>>(x, ws, out, B);
}

// Round 2
// 19.509 us; speedup vs baseline: 1.5518x; 1.5518x over previous
//
#include <hip/hip_runtime.h>

// 4-qubit VQC forward, fully fused single kernel.
// wire w <-> bit (3-w) of the flat amplitude index.
// Final RY layer folded into the measurement:
//   <Z_w>_final = cos(th_w) <Z_w> - sin(th_w) <X_w>   (th = weights[1][w], full angle)

typedef float v2f __attribute__((ext_vector_type(2)));

__global__ __launch_bounds__(256) void qsim_kernel(const float4* __restrict__ x,
                                                   const float* __restrict__ wt,
                                                   float4* __restrict__ out, int B) {
    int i = blockIdx.x * blockDim.x + threadIdx.x;
    if (i >= B) return;

    float4 xv = x[i];

    // uniform weight trig (wt is wave-uniform -> scalar loads; trans ops are cheap)
    float ca1[4], sa1[4], cF[4], sF[4];
#pragma unroll
    for (int q = 0; q < 4; ++q) {
        float a = 0.5f * wt[q];        // layer-1 RY half-angle
        ca1[q] = __cosf(a);
        sa1[q] = __sinf(a);
        float th = wt[4 + q];          // layer-2 RY full angle (folded into measurement)
        cF[q] = __cosf(th);
        sF[q] = __sinf(th);
    }

    // ---- RX product state ----
    float c0 = __cosf(0.5f * xv.x), s0 = __sinf(0.5f * xv.x);
    float c1 = __cosf(0.5f * xv.y), s1 = __sinf(0.5f * xv.y);
    float c2 = __cosf(0.5f * xv.z), s2 = __sinf(0.5f * xv.z);
    float c3 = __cosf(0.5f * xv.w), s3 = __sinf(0.5f * xv.w);

    float l01[4] = {c0 * c1, c0 * s1, s0 * c1, s0 * s1};  // (bit3,bit2) = wires 0,1
    float l23[4] = {c2 * c3, c2 * s3, s2 * c3, s2 * s3};  // (bit1,bit0) = wires 2,3

    // amp[idx] = (-i)^popcount(idx) * product  (compile-time phase pattern)
    v2f amp[16];
#pragma unroll
    for (int idx = 0; idx < 16; ++idx) {
        float p = l01[idx >> 2] * l23[idx & 3];
        int k = ((idx & 1) + ((idx >> 1) & 1) + ((idx >> 2) & 1) + ((idx >> 3) & 1)) & 3;
        v2f a;
        a.x = (k == 0) ? p : ((k == 2) ? -p : 0.0f);
        a.y = (k == 1) ? -p : ((k == 3) ? p : 0.0f);
        amp[idx] = a;
    }

    const int cw[6] = {0, 0, 0, 1, 1, 2};
    const int tw[6] = {1, 2, 3, 2, 3, 3};

    // ---- layer 1: CNOTs + RY(weights[0][w]) ----
#pragma unroll
    for (int q = 0; q < 6; ++q) {
        int mc = 8 >> cw[q], mt = 8 >> tw[q];
#pragma unroll
        for (int idx = 0; idx < 16; ++idx) {
            if ((idx & mc) && !(idx & mt)) {
                int j = idx | mt;
                v2f t = amp[idx]; amp[idx] = amp[j]; amp[j] = t;
            }
        }
    }
#pragma unroll
    for (int q = 0; q < 4; ++q) {
        int m = 8 >> q;
        float ca = ca1[q], sa = sa1[q];
#pragma unroll
        for (int idx = 0; idx < 16; ++idx) {
            if (!(idx & m)) {
                int j = idx | m;
                v2f a0 = amp[idx], a1 = amp[j];
                amp[idx] = ca * a0 - sa * a1;
                amp[j]   = sa * a0 + ca * a1;
            }
        }
    }

    // ---- layer 2: CNOTs only (RY folded into measurement) ----
#pragma unroll
    for (int q = 0; q < 6; ++q) {
        int mc = 8 >> cw[q], mt = 8 >> tw[q];
#pragma unroll
        for (int idx = 0; idx < 16; ++idx) {
            if ((idx & mc) && !(idx & mt)) {
                int j = idx | mt;
                v2f t = amp[idx]; amp[idx] = amp[j]; amp[j] = t;
            }
        }
    }

    // ---- measurement: out_w = cF*<Z_w> - sF*<X_w> ----
    float p[16];
#pragma unroll
    for (int idx = 0; idx < 16; ++idx)
        p[idx] = amp[idx].x * amp[idx].x + amp[idx].y * amp[idx].y;

    float z0 = 0.f, z1 = 0.f, z2 = 0.f, z3 = 0.f;
#pragma unroll
    for (int idx = 0; idx < 16; ++idx) {
        z0 += (idx & 8) ? -p[idx] : p[idx];
        z1 += (idx & 4) ? -p[idx] : p[idx];
        z2 += (idx & 2) ? -p[idx] : p[idx];
        z3 += (idx & 1) ? -p[idx] : p[idx];
    }

    float xe[4] = {0.f, 0.f, 0.f, 0.f};
#pragma unroll
    for (int q = 0; q < 4; ++q) {
        int m = 8 >> q;
#pragma unroll
        for (int idx = 0; idx < 16; ++idx) {
            if (!(idx & m)) {
                int j = idx | m;
                xe[q] += amp[idx].x * amp[j].x + amp[idx].y * amp[j].y;
            }
        }
    }

    float4 ov;
    ov.x = cF[0] * z0 - sF[0] * (2.f * xe[0]);
    ov.y = cF[1] * z1 - sF[1] * (2.f * xe[1]);
    ov.z = cF[2] * z2 - sF[2] * (2.f * xe[2]);
    ov.w = cF[3] * z3 - sF[3] * (2.f * xe[3]);
    out[i] = ov;
}

extern "C" void kernel_launch(void* const* d_in, const int* in_sizes, int n_in,
                              void* d_out, int out_size, void* d_ws, size_t ws_size,
                              hipStream_t stream) {
    const float4* x = (const float4*)d_in[0];   // [B,4]
    const float* w  = (const float*)d_in[1];    // [2,4]
    float4* out = (float4*)d_out;               // [B,4]
    int B = in_sizes[0] / 4;

    qsim_kernel<<<(B + 255) / 256, 256, 0, stream>>>(x, w, out, B);
}

// Round 3
// 18.455 us; speedup vs baseline: 1.6405x; 1.0571x over previous
//
#include <hip/hip_runtime.h>

// 4-qubit VQC forward, fused, 4 samples per thread.
// wire w <-> bit (3-w) of flat amplitude index.
// Layer-2 RY folded into measurement:
//   out_w = cos(th_w) <Z_w> - sin(th_w) <X_w>,  th = weights[1][w]

typedef float v2f __attribute__((ext_vector_type(2)));

#define NS 4  // samples per thread

__global__ __launch_bounds__(256) void qsim_kernel(const float4* __restrict__ x,
                                                   const float* __restrict__ wt,
                                                   float4* __restrict__ out, int B) {
    int tid = blockIdx.x * blockDim.x + threadIdx.x;
    int S = gridDim.x * blockDim.x;

    // ---- issue all sample loads first (coalesced, stride S) ----
    float4 xs[NS];
#pragma unroll
    for (int k = 0; k < NS; ++k) {
        int i = tid + k * S;
        if (i < B) xs[k] = x[i];
    }

    // ---- batch-uniform weight trig (computed once per thread, reused NS times) ----
    float ca1[4], sa1[4], cF[4], sF2[4];
#pragma unroll
    for (int q = 0; q < 4; ++q) {
        float a = 0.5f * wt[q];          // layer-1 RY half-angle
        ca1[q] = __cosf(a);
        sa1[q] = __sinf(a);
        float th = wt[4 + q];            // layer-2 RY full angle (folded)
        cF[q]  = __cosf(th);
        sF2[q] = 2.0f * __sinf(th);      // fold the 2x from <X> here
    }

    const int cw[6] = {0, 0, 0, 1, 1, 2};
    const int tw[6] = {1, 2, 3, 2, 3, 3};

#pragma unroll
    for (int k = 0; k < NS; ++k) {
        int i = tid + k * S;
        if (i >= B) continue;
        float4 xv = xs[k];

        // ---- RX product state ----
        float c0 = __cosf(0.5f * xv.x), s0 = __sinf(0.5f * xv.x);
        float c1 = __cosf(0.5f * xv.y), s1 = __sinf(0.5f * xv.y);
        float c2 = __cosf(0.5f * xv.z), s2 = __sinf(0.5f * xv.z);
        float c3 = __cosf(0.5f * xv.w), s3 = __sinf(0.5f * xv.w);

        float l01[4] = {c0 * c1, c0 * s1, s0 * c1, s0 * s1};
        float l23[4] = {c2 * c3, c2 * s3, s2 * c3, s2 * s3};

        // amp[idx] = (-i)^popcount(idx) * product (compile-time phase; zeros const-fold)
        v2f amp[16];
#pragma unroll
        for (int idx = 0; idx < 16; ++idx) {
            float p = l01[idx >> 2] * l23[idx & 3];
            int kk = ((idx & 1) + ((idx >> 1) & 1) + ((idx >> 2) & 1) + ((idx >> 3) & 1)) & 3;
            v2f a;
            a.x = (kk == 0) ? p : ((kk == 2) ? -p : 0.0f);
            a.y = (kk == 1) ? -p : ((kk == 3) ? p : 0.0f);
            amp[idx] = a;
        }

        // ---- layer 1: CNOTs (register permutation) + RY(weights[0][w]) ----
#pragma unroll
        for (int q = 0; q < 6; ++q) {
            int mc = 8 >> cw[q], mt = 8 >> tw[q];
#pragma unroll
            for (int idx = 0; idx < 16; ++idx) {
                if ((idx & mc) && !(idx & mt)) {
                    int j = idx | mt;
                    v2f t = amp[idx]; amp[idx] = amp[j]; amp[j] = t;
                }
            }
        }
#pragma unroll
        for (int q = 0; q < 4; ++q) {
            int m = 8 >> q;
            float ca = ca1[q], sa = sa1[q];
#pragma unroll
            for (int idx = 0; idx < 16; ++idx) {
                if (!(idx & m)) {
                    int j = idx | m;
                    v2f a0 = amp[idx], a1 = amp[j];
                    amp[idx] = ca * a0 - sa * a1;
                    amp[j]   = sa * a0 + ca * a1;
                }
            }
        }

        // ---- layer 2: CNOTs only ----
#pragma unroll
        for (int q = 0; q < 6; ++q) {
            int mc = 8 >> cw[q], mt = 8 >> tw[q];
#pragma unroll
            for (int idx = 0; idx < 16; ++idx) {
                if ((idx & mc) && !(idx & mt)) {
                    int j = idx | mt;
                    v2f t = amp[idx]; amp[idx] = amp[j]; amp[j] = t;
                }
            }
        }

        // ---- probabilities ----
        float p[16];
#pragma unroll
        for (int idx = 0; idx < 16; ++idx)
            p[idx] = amp[idx].x * amp[idx].x + amp[idx].y * amp[idx].y;

        // ---- shared-partial-sum (WHT) Z reductions ----
        float u[8], uu[4], uuu[2];
        float z3 = 0.f, z2 = 0.f, z1 = 0.f, z0;
#pragma unroll
        for (int j = 0; j < 8; ++j) { z3 += p[2 * j] - p[2 * j + 1]; u[j] = p[2 * j] + p[2 * j + 1]; }
#pragma unroll
        for (int j = 0; j < 4; ++j) { z2 += u[2 * j] - u[2 * j + 1]; uu[j] = u[2 * j] + u[2 * j + 1]; }
#pragma unroll
        for (int j = 0; j < 2; ++j) { z1 += uu[2 * j] - uu[2 * j + 1]; uuu[j] = uu[2 * j] + uu[2 * j + 1]; }
        z0 = uuu[0] - uuu[1];

        // ---- X reductions (packed accumulate) ----
        float xe[4];
#pragma unroll
        for (int q = 0; q < 4; ++q) {
            int m = 8 >> q;
            v2f acc = {0.f, 0.f};
#pragma unroll
            for (int idx = 0; idx < 16; ++idx) {
                if (!(idx & m)) {
                    int j = idx | m;
                    acc += amp[idx] * amp[j];
                }
            }
            xe[q] = acc.x + acc.y;
        }

        float4 ov;
        ov.x = cF[0] * z0 - sF2[0] * xe[0];
        ov.y = cF[1] * z1 - sF2[1] * xe[1];
        ov.z = cF[2] * z2 - sF2[2] * xe[2];
        ov.w = cF[3] * z3 - sF2[3] * xe[3];
        out[i] = ov;
    }
}

extern "C" void kernel_launch(void* const* d_in, const int* in_sizes, int n_in,
                              void* d_out, int out_size, void* d_ws, size_t ws_size,
                              hipStream_t stream) {
    const float4* x = (const float4*)d_in[0];   // [B,4]
    const float* w  = (const float*)d_in[1];    // [2,4]
    float4* out = (float4*)d_out;               // [B,4]
    int B = in_sizes[0] / 4;

    int threads = (B + NS - 1) / NS;
    int blocks = (threads + 255) / 256;
    qsim_kernel<<<blocks, 256, 0, stream>>>(x, w, out, B);
}

// Round 4
// 11.103 us; speedup vs baseline: 2.7267x; 1.6621x over previous
//
#include <hip/hip_runtime.h>

// 4-qubit VQC forward, closed form via Heisenberg-picture Pauli propagation.
// CNOT all-pairs block = GF(2) linear map f(a,b,c,d) = (a, a^b, b^c, c^d).
// Conjugating (cF Z_w - sF X_w) through P, RY1, P yields Pauli strings whose
// expectation on the RX product state factorizes:
//   <Z_q> = cos x_q, <X_q> = 0, <XZ_q> = i sin x_q.
// Result: out_w = batch-uniform-coeff dot products of per-wire cos/sin monomials.

#define NS 4  // samples per thread

__global__ __launch_bounds__(256) void qsim_kernel(const float4* __restrict__ x,
                                                   const float* __restrict__ wt,
                                                   float4* __restrict__ out, int B) {
    int tid = blockIdx.x * blockDim.x + threadIdx.x;
    int S = gridDim.x * blockDim.x;

    // ---- issue all sample loads first (coalesced float4, stride S) ----
    float4 xs[NS];
#pragma unroll
    for (int k = 0; k < NS; ++k) {
        int i = tid + k * S;
        if (i < B) xs[k] = x[i];
    }

    // ---- batch-uniform coefficients (FULL angles; wt[0..3]=layer1, wt[4..7]=layer2) ----
    float A[4], Bq[4], cF[4], sF[4];
#pragma unroll
    for (int q = 0; q < 4; ++q) {
        A[q]  = __cosf(wt[q]);
        Bq[q] = __sinf(wt[q]);
        cF[q] = __cosf(wt[4 + q]);
        sF[q] = __sinf(wt[4 + q]);
    }
    float C0z =  cF[0] * A[0];
    float C0a = -sF[0] * Bq[0] * Bq[1] * Bq[2] * Bq[3];
    float C0b =  sF[0] * A[0] * Bq[1] * A[2] * Bq[3];
    float C0c =  sF[0] * Bq[0] * A[1] * Bq[2] * A[3];
    float C0d =  sF[0] * Bq[0] * Bq[1] * A[2] * Bq[3];
    float C1z =  cF[1] * A[0] * A[1];
    float C1a = -sF[1] * Bq[1] * Bq[2] * Bq[3];
    float C1b =  sF[1] * Bq[1] * A[2] * Bq[3];
    float C1c =  sF[1] * A[1] * Bq[2] * A[3];
    float C2z =  cF[2] * A[1] * A[2];
    float C2a = -sF[2] * Bq[2] * Bq[3];
    float C2b =  sF[2] * A[2] * Bq[3];
    float C3z =  cF[3] * A[2] * A[3];
    float C3y =  cF[3] * Bq[2] * A[3];
    float C3a = -sF[3] * Bq[3];

#pragma unroll
    for (int k = 0; k < NS; ++k) {
        int i = tid + k * S;
        if (i >= B) continue;
        float4 xv = xs[k];

        float g0 = __cosf(xv.x), h0 = __sinf(xv.x);
        float g1 = __cosf(xv.y), h1 = __sinf(xv.y);
        float g2 = __cosf(xv.z), h2 = __sinf(xv.z);
        float g3 = __cosf(xv.w), h3 = __sinf(xv.w);

        float h23 = h2 * h3, h12 = h1 * h2, h01 = h0 * h1;
        float g03 = g0 * g3, g13 = g1 * g3, g23 = g2 * g3;
        float g02 = g0 * g2, g01 = g0 * g1;

        float4 ov;
        ov.x = C0z * g0 + C0a * g3 + C0b * (h01 * g23) + C0c * (g0 * h12) + C0d * (g1 * h23);
        ov.y = C1z * g1 + C1a * g03 + C1b * (g01 * h23) + C1c * h12;
        ov.z = C2z * g02 + C2a * g13 + C2b * h23;
        ov.w = C3z * g13 + C3y * h23 + C3a * g23;
        out[i] = ov;
    }
}

extern "C" void kernel_launch(void* const* d_in, const int* in_sizes, int n_in,
                              void* d_out, int out_size, void* d_ws, size_t ws_size,
                              hipStream_t stream) {
    const float4* x = (const float4*)d_in[0];   // [B,4]
    const float* w  = (const float*)d_in[1];    // [2,4]
    float4* out = (float4*)d_out;               // [B,4]
    int B = in_sizes[0] / 4;

    int threads = (B + NS - 1) / NS;
    int blocks = (threads + 255) / 256;
    qsim_kernel<<<blocks, 256, 0, stream>>>(x, w, out, B);
}